// Round 3
// baseline (575.303 us; speedup 1.0000x reference)
//
#include <hip/hip_runtime.h>
#include <cstdint>

#define DIM 128
#define MTILE 64        // edges per block-tile
#define PAIR_LD 264     // ushorts per pair row (256 + 8 pad, keeps 16B align)
#define H_LD 136        // ushorts per h row  (128 + 8 pad)

typedef __bf16 v8bf __attribute__((ext_vector_type(8)));
typedef float v16f __attribute__((ext_vector_type(16)));

static __device__ __forceinline__ unsigned int f2bf_pack(float a, float b) {
  union { float f; unsigned u; } x, y; x.f = a; y.f = b;
  unsigned lo = (x.u + 0x7FFFu + ((x.u >> 16) & 1u)) >> 16;
  unsigned hi = (y.u + 0x7FFFu + ((y.u >> 16) & 1u)) >> 16;
  return lo | (hi << 16);
}
static __device__ __forceinline__ unsigned short f2bf(float a) {
  union { float f; unsigned u; } x; x.f = a;
  return (unsigned short)((x.u + 0x7FFFu + ((x.u >> 16) & 1u)) >> 16);
}
static __device__ __forceinline__ float bfhi2f(unsigned int hi16) {
  union { unsigned u; float f; } c; c.u = hi16; return c.f;
}

// One fused prep launch:
//  [0, 32768)          : W1 [256][128] -> W1t bf16 [128][256] (transpose+convert)
//  [32768, 49152)      : W2 [128][128] -> W2t bf16 [128][128]
//  [49152, 49152+n8)   : x1 fp32 -> xc1 bf16, 8 elems/thread
//  [.., 49152+2*n8)    : x2 fp32 -> xc2 bf16
__global__ __launch_bounds__(256) void prep_all(
    const float* __restrict__ W1, const float* __restrict__ W2,
    const float* __restrict__ x1, const float* __restrict__ x2,
    unsigned short* __restrict__ W1t, unsigned short* __restrict__ W2t,
    unsigned short* __restrict__ xc1, unsigned short* __restrict__ xc2,
    int n8, int use_cache) {
  int i = blockIdx.x * 256 + threadIdx.x;
  if (i < 32768) {
    int n = i >> 8, k = i & 255;
    W1t[i] = f2bf(W1[k * 128 + n]);
  } else if (i < 49152) {
    int j = i - 32768;
    int n = j >> 7, k = j & 127;
    W2t[j] = f2bf(W2[k * 128 + n]);
  } else if (use_cache) {
    int j = i - 49152;
    const float* xs;
    unsigned short* xd;
    if (j < n8) { xs = x1; xd = xc1; }
    else if (j < 2 * n8) { xs = x2; xd = xc2; j -= n8; }
    else return;
    const float4* s = reinterpret_cast<const float4*>(xs) + (size_t)j * 2;
    float4 f0 = s[0];
    float4 f1 = s[1];
    uint4 pk;
    pk.x = f2bf_pack(f0.x, f0.y);
    pk.y = f2bf_pack(f0.z, f0.w);
    pk.z = f2bf_pack(f1.x, f1.y);
    pk.w = f2bf_pack(f1.z, f1.w);
    reinterpret_cast<uint4*>(xd)[j] = pk;
  }
}

// 2 blocks/CU: VGPR cap 256. Persistent demand ~190 (B1=64, B2=32, xpf=32,
// idxn=8, acc=32, addr ~20) -- fits WITHOUT spill. (256,3) capped at 170 and
// spilled 839 MB of scratch (round-2 regression).
__global__ __launch_bounds__(256, 2) void mlp_edge_kernel(
    const float* __restrict__ x1, const float* __restrict__ x2,
    const int* __restrict__ eidx,
    const unsigned short* __restrict__ W1t, const unsigned short* __restrict__ W2t,
    const float* __restrict__ b1, const float* __restrict__ b2,
    const float* __restrict__ W3, const float* __restrict__ b3,
    float* __restrict__ out, int E, int ntiles,
    const unsigned short* __restrict__ xc1, const unsigned short* __restrict__ xc2,
    int use_cache)
{
  __shared__ unsigned short sm_pair[MTILE * PAIR_LD];  // 33792 B; aliased as h2
  __shared__ unsigned short sm_h1[MTILE * H_LD];       // 17408 B
  __shared__ float sm_w3[4 * 36];                      // 576 B, padded per-part
  unsigned short* sm_h2 = sm_pair;                     // alias (h2 uses H_LD stride)

  const int tid = threadIdx.x;
  const int lane = tid & 63;
  const int wv = tid >> 6;         // wave 0..3 -> n-slice [32*wv, 32*wv+32)
  const int l31 = lane & 31;
  const int l5 = lane >> 5;        // 0/1
  const int nb = wv * 32 + l31;    // this lane's output column n

  // ---- persistent weight fragments (per-wave n-slice) ----
  v8bf B1[16], B2[8];
#pragma unroll
  for (int kt = 0; kt < 16; ++kt)
    B1[kt] = *reinterpret_cast<const v8bf*>(W1t + nb * 256 + kt * 16 + l5 * 8);
#pragma unroll
  for (int kt = 0; kt < 8; ++kt)
    B2[kt] = *reinterpret_cast<const v8bf*>(W2t + nb * 128 + kt * 16 + l5 * 8);
  const float b1v = b1[nb];
  const float b2v = b2[nb];
  const float bias3 = b3[0];

  // ---- W3 in LDS (saves 32 VGPR/thread), padded [part][36] ----
  if (tid < 128) sm_w3[(tid >> 5) * 36 + (tid & 31)] = W3[tid];

  const int rslot = tid >> 4;      // 0..15: row slot within a gather pass
  const int lane16 = tid & 15;     // 16 lanes x 8 elems cover one 128-wide row
  const int part = tid & 3;

  const int tc0 = min(blockIdx.x, ntiles - 1);

  // ---- pipelined gather state (cache mode): depth-1 x-rows, depth-2 eidx ----
  uint4 xpf[8];                    // bf16 x-rows for the CURRENT tile
  int idxn[8];                     // node indices for tile+stride
  if (use_cache) {
    int idxc[8];
#pragma unroll
    for (int p = 0; p < 8; ++p) {
      int el = (p & 3) * 16 + rslot;
      idxc[p] = eidx[(size_t)tc0 * MTILE + el + ((p >= 4) ? E : 0)];
    }
#pragma unroll
    for (int p = 0; p < 8; ++p) {
      const unsigned short* xb = (p >= 4) ? xc2 : xc1;
      xpf[p] = *reinterpret_cast<const uint4*>(xb + (size_t)idxc[p] * DIM + lane16 * 8);
    }
    int tn1 = min(tc0 + (int)gridDim.x, ntiles - 1);
#pragma unroll
    for (int p = 0; p < 8; ++p) {
      int el = (p & 3) * 16 + rslot;
      idxn[p] = eidx[(size_t)tn1 * MTILE + el + ((p >= 4) ? E : 0)];
    }
  }

  for (int tile = blockIdx.x; tile < ntiles; tile += gridDim.x) {
    __syncthreads();  // pair buffer free (prev tile's GEMM3 done reading h2)
    const int e0 = tile * MTILE;

    if (use_cache) {
      // ---- write current tile's prefetched rows, then prefetch next ----
#pragma unroll
      for (int p = 0; p < 8; ++p) {
        int el = (p & 3) * 16 + rslot;
        *reinterpret_cast<uint4*>(&sm_pair[el * PAIR_LD + ((p >= 4) ? 128 : 0) + lane16 * 8]) = xpf[p];
      }
      // x rows for tile+stride (indices already in regs); idx for tile+2*stride
#pragma unroll
      for (int p = 0; p < 8; ++p) {
        const unsigned short* xb = (p >= 4) ? xc2 : xc1;
        xpf[p] = *reinterpret_cast<const uint4*>(xb + (size_t)idxn[p] * DIM + lane16 * 8);
      }
      int t2 = min(tile + 2 * (int)gridDim.x, ntiles - 1);
#pragma unroll
      for (int p = 0; p < 8; ++p) {
        int el = (p & 3) * 16 + rslot;
        idxn[p] = eidx[(size_t)t2 * MTILE + el + ((p >= 4) ? E : 0)];
      }
    } else {
      // ---- fallback: direct fp32 gather + pack ----
#pragma unroll
      for (int p = 0; p < 8; ++p) {
        int rowid = p * 16 + rslot;
        int half = rowid >> 6;
        int el = rowid & 63;
        int e = e0 + el;
        int node = eidx[e + (half ? E : 0)];
        const float* src = (half ? x2 : x1) + (size_t)node * DIM + lane16 * 8;
        float4 f0 = *reinterpret_cast<const float4*>(src);
        float4 f1 = *reinterpret_cast<const float4*>(src + 4);
        uint4 pk;
        pk.x = f2bf_pack(f0.x, f0.y);
        pk.y = f2bf_pack(f0.z, f0.w);
        pk.z = f2bf_pack(f1.x, f1.y);
        pk.w = f2bf_pack(f1.z, f1.w);
        *reinterpret_cast<uint4*>(&sm_pair[el * PAIR_LD + half * 128 + lane16 * 8]) = pk;
      }
    }
    __syncthreads();

    // ---- GEMM1: [64,256] x [256,128] -> relu -> h1 bf16 in LDS ----
    v16f acc0, acc1;
#pragma unroll
    for (int r = 0; r < 16; ++r) { acc0[r] = 0.f; acc1[r] = 0.f; }
#pragma unroll
    for (int kt = 0; kt < 16; ++kt) {
      v8bf a0 = *reinterpret_cast<const v8bf*>(&sm_pair[l31 * PAIR_LD + kt * 16 + l5 * 8]);
      v8bf a1 = *reinterpret_cast<const v8bf*>(&sm_pair[(32 + l31) * PAIR_LD + kt * 16 + l5 * 8]);
      acc0 = __builtin_amdgcn_mfma_f32_32x32x16_bf16(a0, B1[kt], acc0, 0, 0, 0);
      acc1 = __builtin_amdgcn_mfma_f32_32x32x16_bf16(a1, B1[kt], acc1, 0, 0, 0);
    }
#pragma unroll
    for (int r = 0; r < 16; ++r) {
      int m = (r & 3) + 8 * (r >> 2) + 4 * l5;   // C/D row mapping (verified m74/m101)
      sm_h1[m * H_LD + nb] = f2bf(fmaxf(acc0[r] + b1v, 0.f));
      sm_h1[(32 + m) * H_LD + nb] = f2bf(fmaxf(acc1[r] + b1v, 0.f));
    }
    __syncthreads();

    // ---- GEMM2: [64,128] x [128,128] -> relu -> h2 bf16 (aliases sm_pair) ----
    v16f c0, c1;
#pragma unroll
    for (int r = 0; r < 16; ++r) { c0[r] = 0.f; c1[r] = 0.f; }
#pragma unroll
    for (int kt = 0; kt < 8; ++kt) {
      v8bf a0 = *reinterpret_cast<const v8bf*>(&sm_h1[l31 * H_LD + kt * 16 + l5 * 8]);
      v8bf a1 = *reinterpret_cast<const v8bf*>(&sm_h1[(32 + l31) * H_LD + kt * 16 + l5 * 8]);
      c0 = __builtin_amdgcn_mfma_f32_32x32x16_bf16(a0, B2[kt], c0, 0, 0, 0);
      c1 = __builtin_amdgcn_mfma_f32_32x32x16_bf16(a1, B2[kt], c1, 0, 0, 0);
    }
#pragma unroll
    for (int r = 0; r < 16; ++r) {
      int m = (r & 3) + 8 * (r >> 2) + 4 * l5;
      sm_h2[m * H_LD + nb] = f2bf(fmaxf(c0[r] + b2v, 0.f));
      sm_h2[(32 + m) * H_LD + nb] = f2bf(fmaxf(c1[r] + b2v, 0.f));
    }
    __syncthreads();

    // ---- GEMM3: out[e] = h2[e,:] . W3 + b3 ; 4 threads per edge ----
    {
      int el = tid >> 2;                         // 0..63
      const unsigned short* hrow = &sm_h2[el * H_LD + part * 32];
      const float* wrow = &sm_w3[part * 36];
      float sum = 0.f;
#pragma unroll
      for (int j = 0; j < 4; ++j) {
        uint4 u = *reinterpret_cast<const uint4*>(hrow + j * 8);
        float4 wa = *reinterpret_cast<const float4*>(wrow + j * 8);
        float4 wb = *reinterpret_cast<const float4*>(wrow + j * 8 + 4);
        sum += bfhi2f(u.x << 16) * wa.x + bfhi2f(u.x & 0xFFFF0000u) * wa.y;
        sum += bfhi2f(u.y << 16) * wa.z + bfhi2f(u.y & 0xFFFF0000u) * wa.w;
        sum += bfhi2f(u.z << 16) * wb.x + bfhi2f(u.z & 0xFFFF0000u) * wb.y;
        sum += bfhi2f(u.w << 16) * wb.z + bfhi2f(u.w & 0xFFFF0000u) * wb.w;
      }
      sum += __shfl_xor(sum, 1, 64);
      sum += __shfl_xor(sum, 2, 64);
      if (part == 0) out[e0 + el] = sum + bias3;
    }
  }
}

extern "C" void kernel_launch(void* const* d_in, const int* in_sizes, int n_in,
                              void* d_out, int out_size, void* d_ws, size_t ws_size,
                              hipStream_t stream) {
  const float* x1 = (const float*)d_in[0];
  const float* x2 = (const float*)d_in[1];
  const int* eidx = (const int*)d_in[2];
  const float* W1 = (const float*)d_in[3];
  const float* b1 = (const float*)d_in[4];
  const float* W2 = (const float*)d_in[5];
  const float* b2 = (const float*)d_in[6];
  const float* W3 = (const float*)d_in[7];
  const float* b3 = (const float*)d_in[8];
  float* out = (float*)d_out;

  int E = in_sizes[2] / 2;
  if (E <= 0) return;
  int ntiles = E / MTILE;           // E = 1,600,000 divisible by 64
  int nelem = in_sizes[0];          // nodes * DIM
  int n8 = nelem / 8;

  unsigned short* W1t = (unsigned short*)d_ws;         // 32768 bf16
  unsigned short* W2t = W1t + 32768;                   // 16384 bf16
  size_t woff = 98304;                                 // bytes used by weights
  size_t need = woff + 2 * (size_t)nelem * 2;
  int use_cache = (ws_size >= need) ? 1 : 0;
  unsigned short* xc1 = (unsigned short*)((char*)d_ws + woff);
  unsigned short* xc2 = xc1 + nelem;

  int prep_items = 49152 + (use_cache ? 2 * n8 : 0);
  prep_all<<<(prep_items + 255) / 256, 256, 0, stream>>>(
      W1, W2, x1, x2, W1t, W2t, xc1, xc2, n8, use_cache);
  mlp_edge_kernel<<<512, 256, 0, stream>>>(x1, x2, eidx, W1t, W2t,
                                           b1, b2, W3, b3, out, E, ntiles,
                                           xc1, xc2, use_cache);
}

// Round 4
// 373.747 us; speedup vs baseline: 1.5393x; 1.5393x over previous
//
#include <hip/hip_runtime.h>
#include <cstdint>

#define DIM 128
#define MTILE 64        // edges per block-tile
#define PAIR_LD 264     // ushorts per pair row (256 + 8 pad, keeps 16B align)
#define H_LD 136        // ushorts per h row  (128 + 8 pad)

typedef __bf16 v8bf __attribute__((ext_vector_type(8)));
typedef float v16f __attribute__((ext_vector_type(16)));

static __device__ __forceinline__ unsigned int f2bf_pack(float a, float b) {
  union { float f; unsigned u; } x, y; x.f = a; y.f = b;
  unsigned lo = (x.u + 0x7FFFu + ((x.u >> 16) & 1u)) >> 16;
  unsigned hi = (y.u + 0x7FFFu + ((y.u >> 16) & 1u)) >> 16;
  return lo | (hi << 16);
}
static __device__ __forceinline__ unsigned short f2bf(float a) {
  union { float f; unsigned u; } x; x.f = a;
  return (unsigned short)((x.u + 0x7FFFu + ((x.u >> 16) & 1u)) >> 16);
}
static __device__ __forceinline__ float bfhi2f(unsigned int hi16) {
  union { unsigned u; float f; } c; c.u = hi16; return c.f;
}

// One fused prep launch:
//  [0, 32768)          : W1 [256][128] -> W1t bf16 [128][256] (transpose+convert)
//  [32768, 49152)      : W2 [128][128] -> W2t bf16 [128][128]
//  [49152, 49152+n8)   : x1 fp32 -> xc1 bf16, 8 elems/thread
//  [.., 49152+2*n8)    : x2 fp32 -> xc2 bf16
__global__ __launch_bounds__(256) void prep_all(
    const float* __restrict__ W1, const float* __restrict__ W2,
    const float* __restrict__ x1, const float* __restrict__ x2,
    unsigned short* __restrict__ W1t, unsigned short* __restrict__ W2t,
    unsigned short* __restrict__ xc1, unsigned short* __restrict__ xc2,
    int n8, int use_cache) {
  int i = blockIdx.x * 256 + threadIdx.x;
  if (i < 32768) {
    int n = i >> 8, k = i & 255;
    W1t[i] = f2bf(W1[k * 128 + n]);
  } else if (i < 49152) {
    int j = i - 32768;
    int n = j >> 7, k = j & 127;
    W2t[j] = f2bf(W2[k * 128 + n]);
  } else if (use_cache) {
    int j = i - 49152;
    const float* xs;
    unsigned short* xd;
    if (j < n8) { xs = x1; xd = xc1; }
    else if (j < 2 * n8) { xs = x2; xd = xc2; j -= n8; }
    else return;
    const float4* s = reinterpret_cast<const float4*>(xs) + (size_t)j * 2;
    float4 f0 = s[0];
    float4 f1 = s[1];
    uint4 pk;
    pk.x = f2bf_pack(f0.x, f0.y);
    pk.y = f2bf_pack(f0.z, f0.w);
    pk.z = f2bf_pack(f1.x, f1.y);
    pk.w = f2bf_pack(f1.z, f1.w);
    reinterpret_cast<uint4*>(xd)[j] = pk;
  }
}

// Cached-gather main kernel. LESSON (r2/r3): never hold gather payload in
// registers across the MFMA section -> spills (839/805 MB scratch WRITE).
// Only the 8 node indices (depth-1) are prefetched; x-row loads are issued
// and immediately stored to LDS at tile start.
// Grid 768 = 3 blocks/CU (LDS-capped: 52.2 KB x 3 = 157 KB <= 160 KB).
__global__ __launch_bounds__(256, 2) void mlp_edge_cached(
    const int* __restrict__ eidx,
    const unsigned short* __restrict__ W1t, const unsigned short* __restrict__ W2t,
    const float* __restrict__ b1, const float* __restrict__ b2,
    const float* __restrict__ W3, const float* __restrict__ b3,
    float* __restrict__ out, int E, int ntiles,
    const unsigned short* __restrict__ xc1, const unsigned short* __restrict__ xc2)
{
  __shared__ unsigned short sm_pair[MTILE * PAIR_LD];  // 33792 B; aliased as h2
  __shared__ unsigned short sm_h1[MTILE * H_LD];       // 17408 B
  __shared__ float sm_w3[4 * 36];                      // 576 B, padded per-part
  unsigned short* sm_h2 = sm_pair;                     // alias (h2 uses H_LD stride)

  const int tid = threadIdx.x;
  const int lane = tid & 63;
  const int wv = tid >> 6;         // wave 0..3 -> n-slice [32*wv, 32*wv+32)
  const int l31 = lane & 31;
  const int l5 = lane >> 5;        // 0/1
  const int nb = wv * 32 + l31;    // this lane's output column n

  // ---- persistent weight fragments (per-wave n-slice) ----
  v8bf B1[16], B2[8];
#pragma unroll
  for (int kt = 0; kt < 16; ++kt)
    B1[kt] = *reinterpret_cast<const v8bf*>(W1t + nb * 256 + kt * 16 + l5 * 8);
#pragma unroll
  for (int kt = 0; kt < 8; ++kt)
    B2[kt] = *reinterpret_cast<const v8bf*>(W2t + nb * 128 + kt * 16 + l5 * 8);
  const float b1v = b1[nb];
  const float b2v = b2[nb];
  const float bias3 = b3[0];

  // ---- W3 in LDS (saves 32 VGPR/thread), padded [part][36] ----
  if (tid < 128) sm_w3[(tid >> 5) * 36 + (tid & 31)] = W3[tid];

  const int rslot = tid >> 4;      // 0..15: row slot within a gather pass
  const int lane16 = tid & 15;     // 16 lanes x 8 bf16 cover one 128-wide row
  const int part = tid & 3;

  // ---- depth-1 index prefetch (8 scalar ints -- cheap, no spill risk) ----
  int idxr[8];
  if (blockIdx.x < ntiles) {
    const size_t e0 = (size_t)blockIdx.x * MTILE;
#pragma unroll
    for (int p = 0; p < 8; ++p) {
      int el = (p & 3) * 16 + rslot;
      idxr[p] = eidx[e0 + el + ((p >= 4) ? (size_t)E : 0)];
    }
  }

  for (int tile = blockIdx.x; tile < ntiles; tile += gridDim.x) {
    __syncthreads();  // pair buffer free (prev tile's GEMM3 done reading h2)
    const int e0 = tile * MTILE;

    // ---- gather: 1 uint4 (8 bf16) per row-slot; loads then stores ----
    uint4 xv[8];
#pragma unroll
    for (int p = 0; p < 8; ++p) {
      const unsigned short* xb = (p >= 4) ? xc2 : xc1;
      xv[p] = *reinterpret_cast<const uint4*>(xb + (size_t)idxr[p] * DIM + lane16 * 8);
    }
#pragma unroll
    for (int p = 0; p < 8; ++p) {
      int el = (p & 3) * 16 + rslot;
      *reinterpret_cast<uint4*>(&sm_pair[el * PAIR_LD + ((p >= 4) ? 128 : 0) + lane16 * 8]) = xv[p];
    }

    // ---- prefetch next tile's indices (land during GEMMs) ----
    int tn = tile + gridDim.x;
    if (tn < ntiles) {
      const size_t en = (size_t)tn * MTILE;
#pragma unroll
      for (int p = 0; p < 8; ++p) {
        int el = (p & 3) * 16 + rslot;
        idxr[p] = eidx[en + el + ((p >= 4) ? (size_t)E : 0)];
      }
    }
    __syncthreads();

    // ---- GEMM1: [64,256] x [256,128] -> relu -> h1 bf16 in LDS ----
    v16f acc0, acc1;
#pragma unroll
    for (int r = 0; r < 16; ++r) { acc0[r] = 0.f; acc1[r] = 0.f; }
#pragma unroll
    for (int kt = 0; kt < 16; ++kt) {
      v8bf a0 = *reinterpret_cast<const v8bf*>(&sm_pair[l31 * PAIR_LD + kt * 16 + l5 * 8]);
      v8bf a1 = *reinterpret_cast<const v8bf*>(&sm_pair[(32 + l31) * PAIR_LD + kt * 16 + l5 * 8]);
      acc0 = __builtin_amdgcn_mfma_f32_32x32x16_bf16(a0, B1[kt], acc0, 0, 0, 0);
      acc1 = __builtin_amdgcn_mfma_f32_32x32x16_bf16(a1, B1[kt], acc1, 0, 0, 0);
    }
#pragma unroll
    for (int r = 0; r < 16; ++r) {
      int m = (r & 3) + 8 * (r >> 2) + 4 * l5;   // C/D row mapping (verified m74/m101)
      sm_h1[m * H_LD + nb] = f2bf(fmaxf(acc0[r] + b1v, 0.f));
      sm_h1[(32 + m) * H_LD + nb] = f2bf(fmaxf(acc1[r] + b1v, 0.f));
    }
    __syncthreads();

    // ---- GEMM2: [64,128] x [128,128] -> relu -> h2 bf16 (aliases sm_pair) ----
    v16f c0, c1;
#pragma unroll
    for (int r = 0; r < 16; ++r) { c0[r] = 0.f; c1[r] = 0.f; }
#pragma unroll
    for (int kt = 0; kt < 8; ++kt) {
      v8bf a0 = *reinterpret_cast<const v8bf*>(&sm_h1[l31 * H_LD + kt * 16 + l5 * 8]);
      v8bf a1 = *reinterpret_cast<const v8bf*>(&sm_h1[(32 + l31) * H_LD + kt * 16 + l5 * 8]);
      c0 = __builtin_amdgcn_mfma_f32_32x32x16_bf16(a0, B2[kt], c0, 0, 0, 0);
      c1 = __builtin_amdgcn_mfma_f32_32x32x16_bf16(a1, B2[kt], c1, 0, 0, 0);
    }
#pragma unroll
    for (int r = 0; r < 16; ++r) {
      int m = (r & 3) + 8 * (r >> 2) + 4 * l5;
      sm_h2[m * H_LD + nb] = f2bf(fmaxf(c0[r] + b2v, 0.f));
      sm_h2[(32 + m) * H_LD + nb] = f2bf(fmaxf(c1[r] + b2v, 0.f));
    }
    __syncthreads();

    // ---- GEMM3: out[e] = h2[e,:] . W3 + b3 ; 4 threads per edge ----
    {
      int el = tid >> 2;                         // 0..63
      const unsigned short* hrow = &sm_h2[el * H_LD + part * 32];
      const float* wrow = &sm_w3[part * 36];
      float sum = 0.f;
#pragma unroll
      for (int j = 0; j < 4; ++j) {
        uint4 u = *reinterpret_cast<const uint4*>(hrow + j * 8);
        float4 wa = *reinterpret_cast<const float4*>(wrow + j * 8);
        float4 wb = *reinterpret_cast<const float4*>(wrow + j * 8 + 4);
        sum += bfhi2f(u.x << 16) * wa.x + bfhi2f(u.x & 0xFFFF0000u) * wa.y;
        sum += bfhi2f(u.y << 16) * wa.z + bfhi2f(u.y & 0xFFFF0000u) * wa.w;
        sum += bfhi2f(u.z << 16) * wb.x + bfhi2f(u.z & 0xFFFF0000u) * wb.y;
        sum += bfhi2f(u.w << 16) * wb.z + bfhi2f(u.w & 0xFFFF0000u) * wb.w;
      }
      sum += __shfl_xor(sum, 1, 64);
      sum += __shfl_xor(sum, 2, 64);
      if (part == 0) out[e0 + el] = sum + bias3;
    }
  }
}

// Fallback (ws too small for node cache): round-1 structure, fp32 gather+pack.
__global__ __launch_bounds__(256, 2) void mlp_edge_direct(
    const float* __restrict__ x1, const float* __restrict__ x2,
    const int* __restrict__ eidx,
    const unsigned short* __restrict__ W1t, const unsigned short* __restrict__ W2t,
    const float* __restrict__ b1, const float* __restrict__ b2,
    const float* __restrict__ W3, const float* __restrict__ b3,
    float* __restrict__ out, int E, int ntiles)
{
  __shared__ unsigned short sm_pair[MTILE * PAIR_LD];
  __shared__ unsigned short sm_h1[MTILE * H_LD];
  __shared__ float sm_w3[4 * 36];
  unsigned short* sm_h2 = sm_pair;

  const int tid = threadIdx.x;
  const int lane = tid & 63;
  const int wv = tid >> 6;
  const int l31 = lane & 31;
  const int l5 = lane >> 5;
  const int nb = wv * 32 + l31;

  v8bf B1[16], B2[8];
#pragma unroll
  for (int kt = 0; kt < 16; ++kt)
    B1[kt] = *reinterpret_cast<const v8bf*>(W1t + nb * 256 + kt * 16 + l5 * 8);
#pragma unroll
  for (int kt = 0; kt < 8; ++kt)
    B2[kt] = *reinterpret_cast<const v8bf*>(W2t + nb * 128 + kt * 16 + l5 * 8);
  const float b1v = b1[nb];
  const float b2v = b2[nb];
  const float bias3 = b3[0];
  if (tid < 128) sm_w3[(tid >> 5) * 36 + (tid & 31)] = W3[tid];

  const int rslot = tid >> 4;
  const int lane16 = tid & 15;
  const int part = tid & 3;

  for (int tile = blockIdx.x; tile < ntiles; tile += gridDim.x) {
    __syncthreads();
    const int e0 = tile * MTILE;
#pragma unroll
    for (int p = 0; p < 8; ++p) {
      int rowid = p * 16 + rslot;
      int half = rowid >> 6;
      int el = rowid & 63;
      int node = eidx[e0 + el + (half ? E : 0)];
      const float* src = (half ? x2 : x1) + (size_t)node * DIM + lane16 * 8;
      float4 f0 = *reinterpret_cast<const float4*>(src);
      float4 f1 = *reinterpret_cast<const float4*>(src + 4);
      uint4 pk;
      pk.x = f2bf_pack(f0.x, f0.y);
      pk.y = f2bf_pack(f0.z, f0.w);
      pk.z = f2bf_pack(f1.x, f1.y);
      pk.w = f2bf_pack(f1.z, f1.w);
      *reinterpret_cast<uint4*>(&sm_pair[el * PAIR_LD + half * 128 + lane16 * 8]) = pk;
    }
    __syncthreads();

    v16f acc0, acc1;
#pragma unroll
    for (int r = 0; r < 16; ++r) { acc0[r] = 0.f; acc1[r] = 0.f; }
#pragma unroll
    for (int kt = 0; kt < 16; ++kt) {
      v8bf a0 = *reinterpret_cast<const v8bf*>(&sm_pair[l31 * PAIR_LD + kt * 16 + l5 * 8]);
      v8bf a1 = *reinterpret_cast<const v8bf*>(&sm_pair[(32 + l31) * PAIR_LD + kt * 16 + l5 * 8]);
      acc0 = __builtin_amdgcn_mfma_f32_32x32x16_bf16(a0, B1[kt], acc0, 0, 0, 0);
      acc1 = __builtin_amdgcn_mfma_f32_32x32x16_bf16(a1, B1[kt], acc1, 0, 0, 0);
    }
#pragma unroll
    for (int r = 0; r < 16; ++r) {
      int m = (r & 3) + 8 * (r >> 2) + 4 * l5;
      sm_h1[m * H_LD + nb] = f2bf(fmaxf(acc0[r] + b1v, 0.f));
      sm_h1[(32 + m) * H_LD + nb] = f2bf(fmaxf(acc1[r] + b1v, 0.f));
    }
    __syncthreads();

    v16f c0, c1;
#pragma unroll
    for (int r = 0; r < 16; ++r) { c0[r] = 0.f; c1[r] = 0.f; }
#pragma unroll
    for (int kt = 0; kt < 8; ++kt) {
      v8bf a0 = *reinterpret_cast<const v8bf*>(&sm_h1[l31 * H_LD + kt * 16 + l5 * 8]);
      v8bf a1 = *reinterpret_cast<const v8bf*>(&sm_h1[(32 + l31) * H_LD + kt * 16 + l5 * 8]);
      c0 = __builtin_amdgcn_mfma_f32_32x32x16_bf16(a0, B2[kt], c0, 0, 0, 0);
      c1 = __builtin_amdgcn_mfma_f32_32x32x16_bf16(a1, B2[kt], c1, 0, 0, 0);
    }
#pragma unroll
    for (int r = 0; r < 16; ++r) {
      int m = (r & 3) + 8 * (r >> 2) + 4 * l5;
      sm_h2[m * H_LD + nb] = f2bf(fmaxf(c0[r] + b2v, 0.f));
      sm_h2[(32 + m) * H_LD + nb] = f2bf(fmaxf(c1[r] + b2v, 0.f));
    }
    __syncthreads();

    {
      int el = tid >> 2;
      const unsigned short* hrow = &sm_h2[el * H_LD + part * 32];
      const float* wrow = &sm_w3[part * 36];
      float sum = 0.f;
#pragma unroll
      for (int j = 0; j < 4; ++j) {
        uint4 u = *reinterpret_cast<const uint4*>(hrow + j * 8);
        float4 wa = *reinterpret_cast<const float4*>(wrow + j * 8);
        float4 wb = *reinterpret_cast<const float4*>(wrow + j * 8 + 4);
        sum += bfhi2f(u.x << 16) * wa.x + bfhi2f(u.x & 0xFFFF0000u) * wa.y;
        sum += bfhi2f(u.y << 16) * wa.z + bfhi2f(u.y & 0xFFFF0000u) * wa.w;
        sum += bfhi2f(u.z << 16) * wb.x + bfhi2f(u.z & 0xFFFF0000u) * wb.y;
        sum += bfhi2f(u.w << 16) * wb.z + bfhi2f(u.w & 0xFFFF0000u) * wb.w;
      }
      sum += __shfl_xor(sum, 1, 64);
      sum += __shfl_xor(sum, 2, 64);
      if (part == 0) out[e0 + el] = sum + bias3;
    }
  }
}

extern "C" void kernel_launch(void* const* d_in, const int* in_sizes, int n_in,
                              void* d_out, int out_size, void* d_ws, size_t ws_size,
                              hipStream_t stream) {
  const float* x1 = (const float*)d_in[0];
  const float* x2 = (const float*)d_in[1];
  const int* eidx = (const int*)d_in[2];
  const float* W1 = (const float*)d_in[3];
  const float* b1 = (const float*)d_in[4];
  const float* W2 = (const float*)d_in[5];
  const float* b2 = (const float*)d_in[6];
  const float* W3 = (const float*)d_in[7];
  const float* b3 = (const float*)d_in[8];
  float* out = (float*)d_out;

  int E = in_sizes[2] / 2;
  if (E <= 0) return;
  int ntiles = E / MTILE;           // E = 1,600,000 divisible by 64
  int nelem = in_sizes[0];          // nodes * DIM
  int n8 = nelem / 8;

  unsigned short* W1t = (unsigned short*)d_ws;         // 32768 bf16
  unsigned short* W2t = W1t + 32768;                   // 16384 bf16
  size_t woff = 98304;                                 // bytes used by weights
  size_t need = woff + 2 * (size_t)nelem * 2;
  int use_cache = (ws_size >= need) ? 1 : 0;
  unsigned short* xc1 = (unsigned short*)((char*)d_ws + woff);
  unsigned short* xc2 = xc1 + nelem;

  int prep_items = 49152 + (use_cache ? 2 * n8 : 0);
  prep_all<<<(prep_items + 255) / 256, 256, 0, stream>>>(
      W1, W2, x1, x2, W1t, W2t, xc1, xc2, n8, use_cache);

  // grid 768 = 3 blocks/CU (LDS-capped occupancy)
  if (use_cache) {
    mlp_edge_cached<<<768, 256, 0, stream>>>(eidx, W1t, W2t, b1, b2, W3, b3,
                                             out, E, ntiles, xc1, xc2);
  } else {
    mlp_edge_direct<<<768, 256, 0, stream>>>(x1, x2, eidx, W1t, W2t,
                                             b1, b2, W3, b3, out, E, ntiles);
  }
}